// Round 1
// baseline (9352.975 us; speedup 1.0000x reference)
//
#include <hip/hip_runtime.h>
#include <math.h>

// Problem constants
#define NN      50000
#define EE      800000
#define DIN     256
#define HF      128
#define RR      8
#define NHEADS  8
#define DHH     16
#define OUTC    3
#define RG      4            // relations per group
#define NGROUP  (RR / RG)

__device__ inline void atomAddF(float* p, float v) {
#if defined(__gfx90a__) || defined(__gfx940__) || defined(__gfx941__) || defined(__gfx942__) || defined(__gfx950__)
    unsafeAtomicAdd(p, v);
#else
    atomicAdd(p, v);
#endif
}

// monotonic float<->uint encoding for atomicMax on floats
__device__ inline unsigned fenc(float f) {
    unsigned u = __float_as_uint(f);
    return (u & 0x80000000u) ? ~u : (u | 0x80000000u);
}
__device__ inline float fdec(unsigned u) {
    return (u & 0x80000000u) ? __uint_as_float(u & 0x7fffffffu) : __uint_as_float(~u);
}

// ---------------- degree ----------------
__global__ __launch_bounds__(256) void deg_count(const int* __restrict__ tgt,
                                                 const int* __restrict__ et,
                                                 int* __restrict__ deg) {
    int i = blockIdx.x * 256 + threadIdx.x;
    if (i < EE) atomicAdd(&deg[tgt[i] * RR + et[i]], 1);
}

__global__ __launch_bounds__(256) void rinv_kernel(const int* __restrict__ deg,
                                                   float* __restrict__ rinv) {
    int i = blockIdx.x * 256 + threadIdx.x;
    if (i < NN * RR) {
        int d = deg[i];
        rinv[i] = 1.0f / (float)(d > 1 ? d : 1);
    }
}

// ---------------- generic fp32 GEMM: C[M,Nc] = A[M,K] @ B[K,Nc] (+bias)(+acc)(+relu) ----------------
#define GBM 128
#define GBN 64
#define GBK 16

template <bool ACC, bool RELU, bool BIAS>
__global__ __launch_bounds__(256) void gemm_kernel(const float* __restrict__ A,
                                                   const float* __restrict__ B,
                                                   float* __restrict__ C,
                                                   const float* __restrict__ bias,
                                                   int M, int Nc, int K) {
    __shared__ float As[GBK][GBM + 4];
    __shared__ float Bs[GBK][GBN + 4];
    const int tid = threadIdx.x;
    const int m0 = blockIdx.y * GBM;
    const int n0 = blockIdx.x * GBN;
    const int tx = tid & 15;   // col group: 4 cols
    const int ty = tid >> 4;   // row group: 8 rows

    float acc[8][4];
#pragma unroll
    for (int i = 0; i < 8; i++)
#pragma unroll
        for (int j = 0; j < 4; j++) acc[i][j] = 0.f;

    for (int k0 = 0; k0 < K; k0 += GBK) {
        // A tile: 128 rows x 16 k -> 512 float4, 2 per thread
#pragma unroll
        for (int i = 0; i < 2; i++) {
            int fl = tid + i * 256;
            int r  = fl >> 2;
            int kk = (fl & 3) << 2;
            int gm = m0 + r;
            float4 v = make_float4(0.f, 0.f, 0.f, 0.f);
            if (gm < M) v = *reinterpret_cast<const float4*>(&A[(size_t)gm * K + k0 + kk]);
            As[kk + 0][r] = v.x; As[kk + 1][r] = v.y; As[kk + 2][r] = v.z; As[kk + 3][r] = v.w;
        }
        // B tile: 16 k x 64 n -> 256 float4, 1 per thread
        {
            int r  = tid >> 4;
            int nn = (tid & 15) << 2;
            float4 v = *reinterpret_cast<const float4*>(&B[(size_t)(k0 + r) * Nc + n0 + nn]);
            Bs[r][nn + 0] = v.x; Bs[r][nn + 1] = v.y; Bs[r][nn + 2] = v.z; Bs[r][nn + 3] = v.w;
        }
        __syncthreads();
#pragma unroll
        for (int k = 0; k < GBK; k++) {
            float a[8], b[4];
#pragma unroll
            for (int i = 0; i < 8; i++) a[i] = As[k][ty * 8 + i];
#pragma unroll
            for (int j = 0; j < 4; j++) b[j] = Bs[k][tx * 4 + j];
#pragma unroll
            for (int i = 0; i < 8; i++)
#pragma unroll
                for (int j = 0; j < 4; j++) acc[i][j] += a[i] * b[j];
        }
        __syncthreads();
    }

    const int gn = n0 + tx * 4;
#pragma unroll
    for (int i = 0; i < 8; i++) {
        int gm = m0 + ty * 8 + i;
        if (gm >= M) break;
        float4 c = make_float4(acc[i][0], acc[i][1], acc[i][2], acc[i][3]);
        if (BIAS) {
            c.x += bias[gn + 0]; c.y += bias[gn + 1]; c.z += bias[gn + 2]; c.w += bias[gn + 3];
        }
        if (ACC) {
            float4 o = *reinterpret_cast<const float4*>(&C[(size_t)gm * Nc + gn]);
            c.x += o.x; c.y += o.y; c.z += o.z; c.w += o.w;
        }
        if (RELU) {
            c.x = fmaxf(c.x, 0.f); c.y = fmaxf(c.y, 0.f); c.z = fmaxf(c.z, 0.f); c.w = fmaxf(c.w, 0.f);
        }
        *reinterpret_cast<float4*>(&C[(size_t)gm * Nc + gn]) = c;
    }
}

// ---------------- RGCN edge scatter: agg[tgt, et-g*RG, :] += h[src,:] * rinv[tgt, et] ----------------
__global__ __launch_bounds__(256) void rgcn_scatter(const float* __restrict__ h,
                                                    const int* __restrict__ src,
                                                    const int* __restrict__ tgt,
                                                    const int* __restrict__ et,
                                                    const float* __restrict__ rinv,
                                                    float* __restrict__ agg,
                                                    int g) {
    int idx = blockIdx.x * 256 + threadIdx.x;
    if (idx >= EE * 32) return;
    int e  = idx >> 5;
    int j4 = (idx & 31) << 2;
    int r  = et[e] - g * RG;
    if ((unsigned)r >= (unsigned)RG) return;
    int s = src[e], t = tgt[e];
    float sc = rinv[t * RR + g * RG + r];
    float4 v = *reinterpret_cast<const float4*>(&h[(size_t)s * HF + j4]);
    float* dst = &agg[((size_t)t * RG + r) * HF + j4];
    atomAddF(dst + 0, v.x * sc);
    atomAddF(dst + 1, v.y * sc);
    atomAddF(dst + 2, v.z * sc);
    atomAddF(dst + 3, v.w * sc);
}

// ---------------- GAT ----------------
__global__ __launch_bounds__(256) void att_scores(const float* __restrict__ z,
                                                  const float* __restrict__ att,
                                                  float* __restrict__ a_src,
                                                  float* __restrict__ a_tgt) {
    int i = blockIdx.x * 256 + threadIdx.x;
    if (i >= NN * NHEADS) return;
    int n = i >> 3, hd = i & 7;
    const float* zp = &z[(size_t)n * HF + hd * DHH];
    const float* as = &att[hd * 2 * DHH];
    float s = 0.f, t = 0.f;
#pragma unroll
    for (int d = 0; d < DHH; d++) {
        float v = zp[d];
        s += v * as[d];
        t += v * as[DHH + d];
    }
    a_src[i] = s;
    a_tgt[i] = t;
}

__global__ __launch_bounds__(256) void gat_init(unsigned* __restrict__ amax,
                                                float* __restrict__ denom) {
    int i = blockIdx.x * 256 + threadIdx.x;
    if (i < NN * NHEADS) {
        amax[i]  = fenc(-1e30f);
        denom[i] = 0.f;
    }
}

__device__ inline float edge_alpha(const float* a_src, const float* a_tgt, int s, int t, int hd) {
    float a = a_src[s * NHEADS + hd] + a_tgt[t * NHEADS + hd];
    return a > 0.f ? a : 0.2f * a;
}

__global__ __launch_bounds__(256) void edge_max(const int* __restrict__ src,
                                                const int* __restrict__ tgt,
                                                const float* __restrict__ a_src,
                                                const float* __restrict__ a_tgt,
                                                unsigned* __restrict__ amax) {
    int idx = blockIdx.x * 256 + threadIdx.x;
    if (idx >= EE * NHEADS) return;
    int e = idx >> 3, hd = idx & 7;
    int s = src[e], t = tgt[e];
    float a = edge_alpha(a_src, a_tgt, s, t, hd);
    atomicMax(&amax[t * NHEADS + hd], fenc(a));
}

__global__ __launch_bounds__(256) void edge_expsum(const int* __restrict__ src,
                                                   const int* __restrict__ tgt,
                                                   const float* __restrict__ a_src,
                                                   const float* __restrict__ a_tgt,
                                                   const unsigned* __restrict__ amax,
                                                   float* __restrict__ denom) {
    int idx = blockIdx.x * 256 + threadIdx.x;
    if (idx >= EE * NHEADS) return;
    int e = idx >> 3, hd = idx & 7;
    int s = src[e], t = tgt[e];
    float a = edge_alpha(a_src, a_tgt, s, t, hd);
    float m = fdec(amax[t * NHEADS + hd]);
    atomAddF(&denom[t * NHEADS + hd], expf(a - m));
}

__global__ __launch_bounds__(256) void edge_agg(const int* __restrict__ src,
                                                const int* __restrict__ tgt,
                                                const float* __restrict__ a_src,
                                                const float* __restrict__ a_tgt,
                                                const unsigned* __restrict__ amax,
                                                const float* __restrict__ denom,
                                                const float* __restrict__ z,
                                                float* __restrict__ hout) {
    int idx = blockIdx.x * 256 + threadIdx.x;
    if (idx >= EE * NHEADS) return;
    int e = idx >> 3, hd = idx & 7;
    int s = src[e], t = tgt[e];
    float a = edge_alpha(a_src, a_tgt, s, t, hd);
    float m = fdec(amax[t * NHEADS + hd]);
    float den = denom[t * NHEADS + hd];
    float coef = expf(a - m) / fmaxf(den, 1e-16f);
    const float* zs = &z[(size_t)s * HF + hd * DHH];
    float* ho = &hout[(size_t)t * HF + hd * DHH];
#pragma unroll
    for (int d4 = 0; d4 < DHH; d4 += 4) {
        float4 v = *reinterpret_cast<const float4*>(&zs[d4]);
        atomAddF(ho + d4 + 0, v.x * coef);
        atomAddF(ho + d4 + 1, v.y * coef);
        atomAddF(ho + d4 + 2, v.z * coef);
        atomAddF(ho + d4 + 3, v.w * coef);
    }
}

// ---------------- final: logits = (hout+bg)@Wf + bf, log_softmax; one wave per node ----------------
__global__ __launch_bounds__(256) void final_kernel(const float* __restrict__ hout,
                                                    const float* __restrict__ bg,
                                                    const float* __restrict__ Wf,
                                                    const float* __restrict__ bf,
                                                    float* __restrict__ out) {
    int gw = (blockIdx.x * 256 + threadIdx.x) >> 6;
    int lane = threadIdx.x & 63;
    if (gw >= NN) return;
    float p0 = 0.f, p1 = 0.f, p2 = 0.f;
#pragma unroll
    for (int jj = 0; jj < 2; jj++) {
        int j = lane + jj * 64;
        float v = hout[(size_t)gw * HF + j] + bg[j];
        p0 += v * Wf[j * 3 + 0];
        p1 += v * Wf[j * 3 + 1];
        p2 += v * Wf[j * 3 + 2];
    }
#pragma unroll
    for (int off = 32; off > 0; off >>= 1) {
        p0 += __shfl_down(p0, off);
        p1 += __shfl_down(p1, off);
        p2 += __shfl_down(p2, off);
    }
    if (lane == 0) {
        float l0 = p0 + bf[0], l1 = p1 + bf[1], l2 = p2 + bf[2];
        float m = fmaxf(l0, fmaxf(l1, l2));
        float lse = m + logf(expf(l0 - m) + expf(l1 - m) + expf(l2 - m));
        out[(size_t)gw * 3 + 0] = l0 - lse;
        out[(size_t)gw * 3 + 1] = l1 - lse;
        out[(size_t)gw * 3 + 2] = l2 - lse;
    }
}

static inline int cdiv(long long a, int b) { return (int)((a + b - 1) / b); }

extern "C" void kernel_launch(void* const* d_in, const int* in_sizes, int n_in,
                              void* d_out, int out_size, void* d_ws, size_t ws_size,
                              hipStream_t stream) {
    const float* x     = (const float*)d_in[0];
    const int*   ei    = (const int*)d_in[1];
    const int*   etype = (const int*)d_in[2];
    const float* Wp    = (const float*)d_in[3];
    const float* bp    = (const float*)d_in[4];
    const float* W1    = (const float*)d_in[5];
    const float* root1 = (const float*)d_in[6];
    const float* b1    = (const float*)d_in[7];
    const float* W2    = (const float*)d_in[8];
    const float* root2 = (const float*)d_in[9];
    const float* b2    = (const float*)d_in[10];
    const float* Wg    = (const float*)d_in[11];
    const float* att   = (const float*)d_in[12];
    const float* bg    = (const float*)d_in[13];
    const float* Wf    = (const float*)d_in[14];
    const float* bf    = (const float*)d_in[15];

    const int* srcv = ei;
    const int* tgtv = ei + EE;

    float* ws = (float*)d_ws;
    float* hA     = ws + 0;         // 6.4M floats
    float* hB     = ws + 6400000;   // 6.4M
    float* zbuf   = ws + 12800000;  // 6.4M
    float* agg    = ws + 19200000;  // 25.6M (N * RG * H)
    int*   deg    = (int*)(ws + 44800000);   // 0.4M
    float* rinv   = ws + 45200000;  // 0.4M
    float* a_src  = ws + 45600000;  // 0.4M
    float* a_tgt  = ws + 46000000;  // 0.4M
    unsigned* amax = (unsigned*)(ws + 46400000); // 0.4M
    float* denom  = ws + 46800000;  // 0.4M  -> total 47.2M floats = 188.8 MB
    (void)ws_size; (void)in_sizes; (void)n_in; (void)out_size;

    dim3 ggrid(HF / GBN, cdiv(NN, GBM));  // (2, 391)

    // degrees
    hipMemsetAsync(deg, 0, (size_t)NN * RR * 4, stream);
    deg_count<<<cdiv(EE, 256), 256, 0, stream>>>(tgtv, etype, deg);
    rinv_kernel<<<cdiv((long long)NN * RR, 256), 256, 0, stream>>>(deg, rinv);

    // projection: hA = x @ Wp + bp
    gemm_kernel<false, false, true><<<ggrid, 256, 0, stream>>>(x, Wp, hA, bp, NN, HF, DIN);

    // RGCN layer 1: hA -> hB
    gemm_kernel<false, false, true><<<ggrid, 256, 0, stream>>>(hA, root1, hB, b1, NN, HF, HF);
    for (int g = 0; g < NGROUP; g++) {
        hipMemsetAsync(agg, 0, (size_t)NN * RG * HF * 4, stream);
        rgcn_scatter<<<cdiv((long long)EE * 32, 256), 256, 0, stream>>>(hA, srcv, tgtv, etype, rinv, agg, g);
        if (g == NGROUP - 1)
            gemm_kernel<true, true, false><<<ggrid, 256, 0, stream>>>(agg, W1 + (size_t)g * RG * HF * HF, hB, nullptr, NN, HF, RG * HF);
        else
            gemm_kernel<true, false, false><<<ggrid, 256, 0, stream>>>(agg, W1 + (size_t)g * RG * HF * HF, hB, nullptr, NN, HF, RG * HF);
    }

    // RGCN layer 2: hB -> hA
    gemm_kernel<false, false, true><<<ggrid, 256, 0, stream>>>(hB, root2, hA, b2, NN, HF, HF);
    for (int g = 0; g < NGROUP; g++) {
        hipMemsetAsync(agg, 0, (size_t)NN * RG * HF * 4, stream);
        rgcn_scatter<<<cdiv((long long)EE * 32, 256), 256, 0, stream>>>(hB, srcv, tgtv, etype, rinv, agg, g);
        if (g == NGROUP - 1)
            gemm_kernel<true, true, false><<<ggrid, 256, 0, stream>>>(agg, W2 + (size_t)g * RG * HF * HF, hA, nullptr, NN, HF, RG * HF);
        else
            gemm_kernel<true, false, false><<<ggrid, 256, 0, stream>>>(agg, W2 + (size_t)g * RG * HF * HF, hA, nullptr, NN, HF, RG * HF);
    }

    // GAT on hA: z = hA @ Wg (no bias)
    gemm_kernel<false, false, false><<<ggrid, 256, 0, stream>>>(hA, Wg, zbuf, nullptr, NN, HF, HF);
    att_scores<<<cdiv((long long)NN * NHEADS, 256), 256, 0, stream>>>(zbuf, att, a_src, a_tgt);
    gat_init<<<cdiv((long long)NN * NHEADS, 256), 256, 0, stream>>>(amax, denom);
    edge_max<<<cdiv((long long)EE * NHEADS, 256), 256, 0, stream>>>(srcv, tgtv, a_src, a_tgt, amax);
    edge_expsum<<<cdiv((long long)EE * NHEADS, 256), 256, 0, stream>>>(srcv, tgtv, a_src, a_tgt, amax, denom);
    hipMemsetAsync(hB, 0, (size_t)NN * HF * 4, stream);
    edge_agg<<<cdiv((long long)EE * NHEADS, 256), 256, 0, stream>>>(srcv, tgtv, a_src, a_tgt, amax, denom, zbuf, hB);

    // final: logits + log_softmax
    final_kernel<<<cdiv((long long)NN * 64, 256), 256, 0, stream>>>(hB, bg, Wf, bf, (float*)d_out);
}

// Round 2
// 1316.523 us; speedup vs baseline: 7.1043x; 7.1043x over previous
//
#include <hip/hip_runtime.h>
#include <math.h>

// Problem constants
#define NN      50000
#define EE      800000
#define DIN     256
#define HF      128
#define RR      8
#define NHEADS  8
#define DHH     16
#define OUTC    3
#define RG      4            // relations per group
#define NGROUP  (RR / RG)

static inline int cdiv(long long a, int b) { return (int)((a + b - 1) / b); }

// ================= CSR build (by target node) =================

__global__ __launch_bounds__(256) void count_kernel(const int* __restrict__ tgt,
                                                    int* __restrict__ cnt) {
    int i = blockIdx.x * 256 + threadIdx.x;
    if (i < EE) atomicAdd(&cnt[tgt[i]], 1);
}

// single-block exclusive scan of cnt[NN] -> rowptr[NN+1]; also init cursor = row start
__global__ __launch_bounds__(1024) void scan_kernel(const int* __restrict__ cnt,
                                                    int* __restrict__ rowptr,
                                                    int* __restrict__ cursor) {
    __shared__ int sums[1024];
    const int t = threadIdx.x;
    const int CH = (NN + 1023) / 1024;  // 49
    int beg = t * CH;
    int end = beg + CH; if (end > NN) end = NN;
    int s = 0;
    for (int i = beg; i < end; i++) s += cnt[i];
    sums[t] = s;
    __syncthreads();
    // Hillis-Steele inclusive scan over 1024
    for (int off = 1; off < 1024; off <<= 1) {
        int v = (t >= off) ? sums[t - off] : 0;
        __syncthreads();
        sums[t] += v;
        __syncthreads();
    }
    int run = sums[t] - s;  // exclusive prefix at chunk start
    for (int i = beg; i < end; i++) {
        int c = cnt[i];
        rowptr[i] = run;
        cursor[i] = run;
        run += c;
    }
    if (t == 1023) rowptr[NN] = sums[1023];
}

__global__ __launch_bounds__(256) void fill_kernel(const int* __restrict__ src,
                                                   const int* __restrict__ tgt,
                                                   const int* __restrict__ et,
                                                   int* __restrict__ cursor,
                                                   int* __restrict__ csr_src,
                                                   int* __restrict__ csr_rel) {
    int e = blockIdx.x * 256 + threadIdx.x;
    if (e >= EE) return;
    int t = tgt[e];
    int pos = atomicAdd(&cursor[t], 1);
    csr_src[pos] = src[e];
    csr_rel[pos] = et[e];
}

// ================= generic fp32 GEMM: C[M,Nc] = A[M,K] @ B[K,Nc] (+bias)(+acc)(+relu) =================
#define GBM 128
#define GBN 64
#define GBK 16

template <bool ACC, bool RELU, bool BIAS>
__global__ __launch_bounds__(256) void gemm_kernel(const float* __restrict__ A,
                                                   const float* __restrict__ B,
                                                   float* __restrict__ C,
                                                   const float* __restrict__ bias,
                                                   int M, int Nc, int K) {
    __shared__ float As[GBK][GBM + 4];
    __shared__ float Bs[GBK][GBN + 4];
    const int tid = threadIdx.x;
    const int m0 = blockIdx.y * GBM;
    const int n0 = blockIdx.x * GBN;
    const int tx = tid & 15;   // col group: 4 cols
    const int ty = tid >> 4;   // row group: 8 rows

    float acc[8][4];
#pragma unroll
    for (int i = 0; i < 8; i++)
#pragma unroll
        for (int j = 0; j < 4; j++) acc[i][j] = 0.f;

    for (int k0 = 0; k0 < K; k0 += GBK) {
#pragma unroll
        for (int i = 0; i < 2; i++) {
            int fl = tid + i * 256;
            int r  = fl >> 2;
            int kk = (fl & 3) << 2;
            int gm = m0 + r;
            float4 v = make_float4(0.f, 0.f, 0.f, 0.f);
            if (gm < M) v = *reinterpret_cast<const float4*>(&A[(size_t)gm * K + k0 + kk]);
            As[kk + 0][r] = v.x; As[kk + 1][r] = v.y; As[kk + 2][r] = v.z; As[kk + 3][r] = v.w;
        }
        {
            int r  = tid >> 4;
            int nn = (tid & 15) << 2;
            float4 v = *reinterpret_cast<const float4*>(&B[(size_t)(k0 + r) * Nc + n0 + nn]);
            Bs[r][nn + 0] = v.x; Bs[r][nn + 1] = v.y; Bs[r][nn + 2] = v.z; Bs[r][nn + 3] = v.w;
        }
        __syncthreads();
#pragma unroll
        for (int k = 0; k < GBK; k++) {
            float a[8], b[4];
#pragma unroll
            for (int i = 0; i < 8; i++) a[i] = As[k][ty * 8 + i];
#pragma unroll
            for (int j = 0; j < 4; j++) b[j] = Bs[k][tx * 4 + j];
#pragma unroll
            for (int i = 0; i < 8; i++)
#pragma unroll
                for (int j = 0; j < 4; j++) acc[i][j] += a[i] * b[j];
        }
        __syncthreads();
    }

    const int gn = n0 + tx * 4;
#pragma unroll
    for (int i = 0; i < 8; i++) {
        int gm = m0 + ty * 8 + i;
        if (gm >= M) break;
        float4 c = make_float4(acc[i][0], acc[i][1], acc[i][2], acc[i][3]);
        if (BIAS) {
            c.x += bias[gn + 0]; c.y += bias[gn + 1]; c.z += bias[gn + 2]; c.w += bias[gn + 3];
        }
        if (ACC) {
            float4 o = *reinterpret_cast<const float4*>(&C[(size_t)gm * Nc + gn]);
            c.x += o.x; c.y += o.y; c.z += o.z; c.w += o.w;
        }
        if (RELU) {
            c.x = fmaxf(c.x, 0.f); c.y = fmaxf(c.y, 0.f); c.z = fmaxf(c.z, 0.f); c.w = fmaxf(c.w, 0.f);
        }
        *reinterpret_cast<float4*>(&C[(size_t)gm * Nc + gn]) = c;
    }
}

// ================= RGCN gather-aggregate (wave per target node) =================
// agg[t, rg, :] = (1/max(deg,1)) * sum_{e: tgt=t, rel = g*RG+rg} h[src_e, :]
__global__ __launch_bounds__(256) void rgcn_agg(const float* __restrict__ h,
                                                const int* __restrict__ rowptr,
                                                const int* __restrict__ csr_src,
                                                const int* __restrict__ csr_rel,
                                                float* __restrict__ agg,
                                                int g) {
    int w = (blockIdx.x * 256 + threadIdx.x) >> 6;
    if (w >= NN) return;
    int lane = threadIdx.x & 63;
    int c0 = lane * 2;
    int beg = rowptr[w], end = rowptr[w + 1];
    int rbase = g * RG;
    float2 a0 = {0.f, 0.f}, a1 = {0.f, 0.f}, a2 = {0.f, 0.f}, a3 = {0.f, 0.f};
    int n0 = 0, n1 = 0, n2 = 0, n3 = 0;
    for (int e = beg; e < end; e++) {
        int r = csr_rel[e] - rbase;
        if ((unsigned)r >= (unsigned)RG) continue;
        int s = csr_src[e];
        float2 v = *reinterpret_cast<const float2*>(&h[(size_t)s * HF + c0]);
        if (r == 0)      { a0.x += v.x; a0.y += v.y; n0++; }
        else if (r == 1) { a1.x += v.x; a1.y += v.y; n1++; }
        else if (r == 2) { a2.x += v.x; a2.y += v.y; n2++; }
        else             { a3.x += v.x; a3.y += v.y; n3++; }
    }
    float s0 = 1.f / (float)(n0 > 1 ? n0 : 1);
    float s1 = 1.f / (float)(n1 > 1 ? n1 : 1);
    float s2 = 1.f / (float)(n2 > 1 ? n2 : 1);
    float s3 = 1.f / (float)(n3 > 1 ? n3 : 1);
    float* o = &agg[(size_t)w * RG * HF + c0];
    *reinterpret_cast<float2*>(o + 0 * HF) = make_float2(a0.x * s0, a0.y * s0);
    *reinterpret_cast<float2*>(o + 1 * HF) = make_float2(a1.x * s1, a1.y * s1);
    *reinterpret_cast<float2*>(o + 2 * HF) = make_float2(a2.x * s2, a2.y * s2);
    *reinterpret_cast<float2*>(o + 3 * HF) = make_float2(a3.x * s3, a3.y * s3);
}

// ================= GAT per-node attention scores =================
__global__ __launch_bounds__(256) void att_scores(const float* __restrict__ z,
                                                  const float* __restrict__ att,
                                                  float* __restrict__ a_src,
                                                  float* __restrict__ a_tgt) {
    int i = blockIdx.x * 256 + threadIdx.x;
    if (i >= NN * NHEADS) return;
    int n = i >> 3, hd = i & 7;
    const float* zp = &z[(size_t)n * HF + hd * DHH];
    const float* as = &att[hd * 2 * DHH];
    float s = 0.f, t = 0.f;
#pragma unroll
    for (int d = 0; d < DHH; d++) {
        float v = zp[d];
        s += v * as[d];
        t += v * as[DHH + d];
    }
    a_src[i] = s;
    a_tgt[i] = t;
}

// ================= GAT: wave per node, online softmax + fused Wf GEMV + log_softmax =================
__global__ __launch_bounds__(256) void gat_kernel(const int* __restrict__ rowptr,
                                                  const int* __restrict__ csr_src,
                                                  const float* __restrict__ a_src,
                                                  const float* __restrict__ a_tgt,
                                                  const float* __restrict__ z,
                                                  const float* __restrict__ bg,
                                                  const float* __restrict__ Wf,
                                                  const float* __restrict__ bf,
                                                  float* __restrict__ out) {
    int w = (blockIdx.x * 256 + threadIdx.x) >> 6;
    if (w >= NN) return;
    int lane = threadIdx.x & 63;
    int hd = lane >> 3;        // head for this lane's columns
    int c0 = lane * 2;         // 2 consecutive cols of the 128-wide row
    float at = a_tgt[w * NHEADS + hd];
    int beg = rowptr[w], end = rowptr[w + 1];

    float m = -1e30f, l = 0.f;
    float ax = 0.f, ay = 0.f;
    for (int e = beg; e < end; e++) {
        int s = csr_src[e];
        float a = a_src[s * NHEADS + hd] + at;
        a = a > 0.f ? a : 0.2f * a;
        float mn = fmaxf(m, a);
        float sc  = __expf(m - mn);   // first iter: exp(-inf)=0
        float wgt = __expf(a - mn);
        l = l * sc + wgt;
        float2 zv = *reinterpret_cast<const float2*>(&z[(size_t)s * HF + c0]);
        ax = ax * sc + zv.x * wgt;
        ay = ay * sc + zv.y * wgt;
        m = mn;
    }
    float inv = 1.f / fmaxf(l, 1e-16f);
    float vx = ax * inv + bg[c0];
    float vy = ay * inv + bg[c0 + 1];

    // logits: p[c] = sum_j v[j] * Wf[j*3+c]
    float p0 = vx * Wf[c0 * 3 + 0] + vy * Wf[(c0 + 1) * 3 + 0];
    float p1 = vx * Wf[c0 * 3 + 1] + vy * Wf[(c0 + 1) * 3 + 1];
    float p2 = vx * Wf[c0 * 3 + 2] + vy * Wf[(c0 + 1) * 3 + 2];
#pragma unroll
    for (int off = 32; off > 0; off >>= 1) {
        p0 += __shfl_xor(p0, off);
        p1 += __shfl_xor(p1, off);
        p2 += __shfl_xor(p2, off);
    }
    if (lane == 0) {
        float l0 = p0 + bf[0], l1 = p1 + bf[1], l2 = p2 + bf[2];
        float mm = fmaxf(l0, fmaxf(l1, l2));
        float lse = mm + logf(expf(l0 - mm) + expf(l1 - mm) + expf(l2 - mm));
        out[(size_t)w * 3 + 0] = l0 - lse;
        out[(size_t)w * 3 + 1] = l1 - lse;
        out[(size_t)w * 3 + 2] = l2 - lse;
    }
}

// ================= launch =================
extern "C" void kernel_launch(void* const* d_in, const int* in_sizes, int n_in,
                              void* d_out, int out_size, void* d_ws, size_t ws_size,
                              hipStream_t stream) {
    const float* x     = (const float*)d_in[0];
    const int*   ei    = (const int*)d_in[1];
    const int*   etype = (const int*)d_in[2];
    const float* Wp    = (const float*)d_in[3];
    const float* bp    = (const float*)d_in[4];
    const float* W1    = (const float*)d_in[5];
    const float* root1 = (const float*)d_in[6];
    const float* b1    = (const float*)d_in[7];
    const float* W2    = (const float*)d_in[8];
    const float* root2 = (const float*)d_in[9];
    const float* b2    = (const float*)d_in[10];
    const float* Wg    = (const float*)d_in[11];
    const float* att   = (const float*)d_in[12];
    const float* bg    = (const float*)d_in[13];
    const float* Wf    = (const float*)d_in[14];
    const float* bf    = (const float*)d_in[15];
    (void)in_sizes; (void)n_in; (void)out_size; (void)ws_size;

    const int* srcv = ei;
    const int* tgtv = ei + EE;

    float* ws = (float*)d_ws;
    float* hA      = ws + 0;          // 6.4M floats (25.6 MB)
    float* hB      = ws + 6400000;    // 6.4M
    float* agg     = ws + 12800000;   // N*RG*HF = 25.6M floats (102.4 MB)
    // GAT-phase buffers alias agg (RGCN done by then)
    float* zbuf    = agg;             // 6.4M
    float* a_src   = agg + 6400000;   // 0.4M
    float* a_tgt   = agg + 6800000;   // 0.4M
    int*   csr_src = (int*)(ws + 38400000);  // 0.8M ints
    int*   csr_rel = (int*)(ws + 39200000);  // 0.8M
    int*   rowptr  = (int*)(ws + 40000000);  // 50001 ints
    int*   cursor  = (int*)(ws + 40060000);  // 50000 ints (doubles as cnt)
    // total ≈ 40.11M floats ≈ 160.5 MB

    // ---- CSR build ----
    hipMemsetAsync(cursor, 0, (size_t)NN * 4, stream);
    count_kernel<<<cdiv(EE, 256), 256, 0, stream>>>(tgtv, cursor);
    scan_kernel<<<1, 1024, 0, stream>>>(cursor, rowptr, cursor);
    fill_kernel<<<cdiv(EE, 256), 256, 0, stream>>>(srcv, tgtv, etype, cursor, csr_src, csr_rel);

    dim3 ggrid(HF / GBN, cdiv(NN, GBM));  // (2, 391)
    const int nwgrid = cdiv(NN, 4);       // wave-per-node kernels, 4 waves/block

    // ---- projection: hA = x @ Wp + bp ----
    gemm_kernel<false, false, true><<<ggrid, 256, 0, stream>>>(x, Wp, hA, bp, NN, HF, DIN);

    // ---- RGCN layer 1: hA -> hB ----
    gemm_kernel<false, false, true><<<ggrid, 256, 0, stream>>>(hA, root1, hB, b1, NN, HF, HF);
    for (int g = 0; g < NGROUP; g++) {
        rgcn_agg<<<nwgrid, 256, 0, stream>>>(hA, rowptr, csr_src, csr_rel, agg, g);
        if (g == NGROUP - 1)
            gemm_kernel<true, true, false><<<ggrid, 256, 0, stream>>>(agg, W1 + (size_t)g * RG * HF * HF, hB, nullptr, NN, HF, RG * HF);
        else
            gemm_kernel<true, false, false><<<ggrid, 256, 0, stream>>>(agg, W1 + (size_t)g * RG * HF * HF, hB, nullptr, NN, HF, RG * HF);
    }

    // ---- RGCN layer 2: hB -> hA ----
    gemm_kernel<false, false, true><<<ggrid, 256, 0, stream>>>(hB, root2, hA, b2, NN, HF, HF);
    for (int g = 0; g < NGROUP; g++) {
        rgcn_agg<<<nwgrid, 256, 0, stream>>>(hB, rowptr, csr_src, csr_rel, agg, g);
        if (g == NGROUP - 1)
            gemm_kernel<true, true, false><<<ggrid, 256, 0, stream>>>(agg, W2 + (size_t)g * RG * HF * HF, hA, nullptr, NN, HF, RG * HF);
        else
            gemm_kernel<true, false, false><<<ggrid, 256, 0, stream>>>(agg, W2 + (size_t)g * RG * HF * HF, hA, nullptr, NN, HF, RG * HF);
    }

    // ---- GAT ----
    gemm_kernel<false, false, false><<<ggrid, 256, 0, stream>>>(hA, Wg, zbuf, nullptr, NN, HF, HF);
    att_scores<<<cdiv((long long)NN * NHEADS, 256), 256, 0, stream>>>(zbuf, att, a_src, a_tgt);
    gat_kernel<<<nwgrid, 256, 0, stream>>>(rowptr, csr_src, a_src, a_tgt, zbuf, bg, Wf, bf, (float*)d_out);
}

// Round 4
// 768.147 us; speedup vs baseline: 12.1760x; 1.7139x over previous
//
#include <hip/hip_runtime.h>
#include <math.h>

// Problem constants
#define NN      50000
#define EE      800000
#define DIN     256
#define HF      128
#define RR      8
#define NHEADS  8
#define DHH     16
#define OUTC    3

static inline int cdiv(long long a, int b) { return (int)((a + b - 1) / b); }

typedef __attribute__((ext_vector_type(8))) short short8;
typedef __attribute__((ext_vector_type(4))) float f32x4;

__device__ inline float bf2f(unsigned short u) {
    unsigned v = ((unsigned)u) << 16;
    return __uint_as_float(v);
}
__device__ inline unsigned short f2bf(float f) {
    unsigned u = __float_as_uint(f);
    u += 0x7fffu + ((u >> 16) & 1u);   // round-to-nearest-even
    return (unsigned short)(u >> 16);
}

// ================= converts =================
__global__ __launch_bounds__(256) void cvt_x_kernel(const float* __restrict__ x,
                                                    unsigned short* __restrict__ xb) {
    int i = (blockIdx.x * 256 + threadIdx.x) * 4;
    if (i >= NN * DIN) return;
    float4 v = *reinterpret_cast<const float4*>(&x[i]);
    ushort4 o;
    o.x = f2bf(v.x); o.y = f2bf(v.y); o.z = f2bf(v.z); o.w = f2bf(v.w);
    *reinterpret_cast<ushort4*>(&xb[i]) = o;
}

// src fp32 [K][128] -> dsthi/dstlo [128][ldk] bf16 split at col offset k0
__global__ __launch_bounds__(256) void trans_split_kernel(const float* __restrict__ src,
                                                          unsigned short* __restrict__ dsthi,
                                                          unsigned short* __restrict__ dstlo,
                                                          int K, int k0, int ldk) {
    int i = blockIdx.x * 256 + threadIdx.x;
    if (i >= K * 128) return;
    int k = i >> 7, n = i & 127;
    float f = src[(size_t)k * 128 + n];
    unsigned short hi = f2bf(f);
    unsigned short lo = f2bf(f - bf2f(hi));
    dsthi[(size_t)n * ldk + k0 + k] = hi;
    dstlo[(size_t)n * ldk + k0 + k] = lo;
}

// ================= CSR build (by target node) =================
__global__ __launch_bounds__(256) void count_kernel(const int* __restrict__ tgt,
                                                    int* __restrict__ cnt) {
    int i = blockIdx.x * 256 + threadIdx.x;
    if (i < EE) atomicAdd(&cnt[tgt[i]], 1);
}

__global__ __launch_bounds__(1024) void scan_kernel(const int* __restrict__ cnt,
                                                    int* __restrict__ rowptr,
                                                    int* __restrict__ cursor) {
    __shared__ int sums[1024];
    const int t = threadIdx.x;
    const int CH = (NN + 1023) / 1024;
    int beg = t * CH;
    int end = beg + CH; if (end > NN) end = NN;
    int s = 0;
    for (int i = beg; i < end; i++) s += cnt[i];
    sums[t] = s;
    __syncthreads();
    for (int off = 1; off < 1024; off <<= 1) {
        int v = (t >= off) ? sums[t - off] : 0;
        __syncthreads();
        sums[t] += v;
        __syncthreads();
    }
    int run = sums[t] - s;
    for (int i = beg; i < end; i++) {
        int c = cnt[i];
        rowptr[i] = run;
        cursor[i] = run;
        run += c;
    }
    if (t == 1023) rowptr[NN] = sums[1023];
}

__global__ __launch_bounds__(256) void fill_kernel(const int* __restrict__ src,
                                                   const int* __restrict__ tgt,
                                                   const int* __restrict__ et,
                                                   int* __restrict__ cursor,
                                                   int* __restrict__ csr_src,
                                                   int* __restrict__ csr_rel) {
    int e = blockIdx.x * 256 + threadIdx.x;
    if (e >= EE) return;
    int t = tgt[e];
    int pos = atomicAdd(&cursor[t], 1);
    csr_src[pos] = src[e];
    csr_rel[pos] = et[e];
}

// ================= bf16 MFMA GEMM with split-B (hi+lo):  C[M,128](bf16) = A[M,K](bf16) @ (Bhi+Blo)^T =================
#define BK 32
#define APAD 40   // padded LDS row (ushorts)

template <bool BIAS, bool RELU>
__global__ __launch_bounds__(256) void gemm_mfma(const unsigned short* __restrict__ A, int lda,
                                                 const unsigned short* __restrict__ Bthi,
                                                 const unsigned short* __restrict__ Btlo, int ldk,
                                                 unsigned short* __restrict__ C,
                                                 const float* __restrict__ bias,
                                                 int M, int K) {
    __shared__ unsigned short As[128][APAD];
    __shared__ unsigned short Bh[128][APAD];
    __shared__ unsigned short Bl[128][APAD];
    const int tid  = threadIdx.x;
    const int m0   = blockIdx.x * 128;
    const int w    = tid >> 6;
    const int lane = tid & 63;
    const int lrow = lane & 15;
    const int q    = lane >> 4;

    f32x4 acc[2][8];
#pragma unroll
    for (int t = 0; t < 2; t++)
#pragma unroll
        for (int c = 0; c < 8; c++) acc[t][c] = (f32x4){0.f, 0.f, 0.f, 0.f};

    const int srow  = tid >> 1;
    const int spart = (tid & 1) * 16;

    for (int k0 = 0; k0 < K; k0 += BK) {
        {
            int gm = m0 + srow;
            uint4 v  = make_uint4(0u, 0u, 0u, 0u);
            uint4 v2 = make_uint4(0u, 0u, 0u, 0u);
            if (gm < M) {
                v  = *reinterpret_cast<const uint4*>(&A[(size_t)gm * lda + k0 + spart]);
                v2 = *reinterpret_cast<const uint4*>(&A[(size_t)gm * lda + k0 + spart + 8]);
            }
            *reinterpret_cast<uint4*>(&As[srow][spart])     = v;
            *reinterpret_cast<uint4*>(&As[srow][spart + 8]) = v2;
        }
        {
            uint4 v  = *reinterpret_cast<const uint4*>(&Bthi[(size_t)srow * ldk + k0 + spart]);
            uint4 v2 = *reinterpret_cast<const uint4*>(&Bthi[(size_t)srow * ldk + k0 + spart + 8]);
            *reinterpret_cast<uint4*>(&Bh[srow][spart])     = v;
            *reinterpret_cast<uint4*>(&Bh[srow][spart + 8]) = v2;
        }
        {
            uint4 v  = *reinterpret_cast<const uint4*>(&Btlo[(size_t)srow * ldk + k0 + spart]);
            uint4 v2 = *reinterpret_cast<const uint4*>(&Btlo[(size_t)srow * ldk + k0 + spart + 8]);
            *reinterpret_cast<uint4*>(&Bl[srow][spart])     = v;
            *reinterpret_cast<uint4*>(&Bl[srow][spart + 8]) = v2;
        }
        __syncthreads();

        short8 afr[2];
#pragma unroll
        for (int t = 0; t < 2; t++)
            afr[t] = *reinterpret_cast<const short8*>(&As[w * 32 + t * 16 + lrow][q * 8]);
#pragma unroll
        for (int c = 0; c < 8; c++) {
            short8 bh = *reinterpret_cast<const short8*>(&Bh[c * 16 + lrow][q * 8]);
            short8 bl = *reinterpret_cast<const short8*>(&Bl[c * 16 + lrow][q * 8]);
#pragma unroll
            for (int t = 0; t < 2; t++) {
                acc[t][c] = __builtin_amdgcn_mfma_f32_16x16x32_bf16(afr[t], bl, acc[t][c], 0, 0, 0);
                acc[t][c] = __builtin_amdgcn_mfma_f32_16x16x32_bf16(afr[t], bh, acc[t][c], 0, 0, 0);
            }
        }
        __syncthreads();
    }

#pragma unroll
    for (int t = 0; t < 2; t++) {
#pragma unroll
        for (int r = 0; r < 4; r++) {
            int gm = m0 + w * 32 + t * 16 + q * 4 + r;
            if (gm >= M) continue;
#pragma unroll
            for (int c = 0; c < 8; c++) {
                int gn = c * 16 + lrow;
                float v = acc[t][c][r];
                if (BIAS) v += bias[gn];
                if (RELU) v = fmaxf(v, 0.f);
                C[(size_t)gm * HF + gn] = f2bf(v);
            }
        }
    }
}

// ================= RGCN gather-aggregate, all 8 relations + self row, one pass =================
// agg[t, r, :] = mean_{e: tgt=t, rel=r} h[src_e, :]  for r<8;  agg[t, 8, :] = h[t, :]
__global__ __launch_bounds__(256) void rgcn_agg_all(const unsigned short* __restrict__ h,
                                                    const int* __restrict__ rowptr,
                                                    const int* __restrict__ csr_src,
                                                    const int* __restrict__ csr_rel,
                                                    unsigned short* __restrict__ agg) {
    int w = (blockIdx.x * 256 + threadIdx.x) >> 6;
    if (w >= NN) return;
    int lane = threadIdx.x & 63;
    int c0 = lane * 2;
    int beg = rowptr[w], end = rowptr[w + 1];
    float ax[RR], ay[RR];
    int cnt[RR];
#pragma unroll
    for (int r = 0; r < RR; r++) { ax[r] = 0.f; ay[r] = 0.f; cnt[r] = 0; }
    for (int e = beg; e < end; e++) {
        int r = csr_rel[e];
        int s = csr_src[e];
        unsigned hv = *reinterpret_cast<const unsigned*>(&h[(size_t)s * HF + c0]);
        float f0 = bf2f((unsigned short)(hv & 0xffffu));
        float f1 = bf2f((unsigned short)(hv >> 16));
#pragma unroll
        for (int rr = 0; rr < RR; rr++) {
            if (r == rr) { ax[rr] += f0; ay[rr] += f1; cnt[rr]++; }
        }
    }
    unsigned short* o = &agg[(size_t)w * ((RR + 1) * HF)];
#pragma unroll
    for (int r = 0; r < RR; r++) {
        float inv = 1.f / (float)(cnt[r] > 1 ? cnt[r] : 1);
        unsigned packed = (unsigned)f2bf(ax[r] * inv) | ((unsigned)f2bf(ay[r] * inv) << 16);
        *reinterpret_cast<unsigned*>(&o[r * HF + c0]) = packed;
    }
    // self row (exact copy) -> block 8 (multiplied by root in the fused GEMM)
    unsigned self = *reinterpret_cast<const unsigned*>(&h[(size_t)w * HF + c0]);
    *reinterpret_cast<unsigned*>(&o[RR * HF + c0]) = self;
}

// ================= GAT per-node attention scores (z bf16) =================
__global__ __launch_bounds__(256) void att_scores(const unsigned short* __restrict__ z,
                                                  const float* __restrict__ att,
                                                  float* __restrict__ a_src,
                                                  float* __restrict__ a_tgt) {
    int i = blockIdx.x * 256 + threadIdx.x;
    if (i >= NN * NHEADS) return;
    int n = i >> 3, hd = i & 7;
    const unsigned short* zp = &z[(size_t)n * HF + hd * DHH];
    const float* as = &att[hd * 2 * DHH];
    float s = 0.f, t = 0.f;
#pragma unroll
    for (int d = 0; d < DHH; d++) {
        float v = bf2f(zp[d]);
        s += v * as[d];
        t += v * as[DHH + d];
    }
    a_src[i] = s;
    a_tgt[i] = t;
}

// ================= GAT: wave per node, online softmax + fused Wf GEMV + log_softmax =================
__global__ __launch_bounds__(256) void gat_kernel(const int* __restrict__ rowptr,
                                                  const int* __restrict__ csr_src,
                                                  const float* __restrict__ a_src,
                                                  const float* __restrict__ a_tgt,
                                                  const unsigned short* __restrict__ z,
                                                  const float* __restrict__ bg,
                                                  const float* __restrict__ Wf,
                                                  const float* __restrict__ bf,
                                                  float* __restrict__ out) {
    int w = (blockIdx.x * 256 + threadIdx.x) >> 6;
    if (w >= NN) return;
    int lane = threadIdx.x & 63;
    int hd = lane >> 3;
    int c0 = lane * 2;
    float at = a_tgt[w * NHEADS + hd];
    int beg = rowptr[w], end = rowptr[w + 1];

    float m = -1e30f, l = 0.f;
    float ax = 0.f, ay = 0.f;
    for (int e = beg; e < end; e++) {
        int s = csr_src[e];
        float a = a_src[s * NHEADS + hd] + at;
        a = a > 0.f ? a : 0.2f * a;
        float mn = fmaxf(m, a);
        float sc  = __expf(m - mn);
        float wgt = __expf(a - mn);
        l = l * sc + wgt;
        unsigned zv = *reinterpret_cast<const unsigned*>(&z[(size_t)s * HF + c0]);
        float zx = bf2f((unsigned short)(zv & 0xffffu));
        float zy = bf2f((unsigned short)(zv >> 16));
        ax = ax * sc + zx * wgt;
        ay = ay * sc + zy * wgt;
        m = mn;
    }
    float inv = 1.f / fmaxf(l, 1e-16f);
    float vx = ax * inv + bg[c0];
    float vy = ay * inv + bg[c0 + 1];

    float p0 = vx * Wf[c0 * 3 + 0] + vy * Wf[(c0 + 1) * 3 + 0];
    float p1 = vx * Wf[c0 * 3 + 1] + vy * Wf[(c0 + 1) * 3 + 1];
    float p2 = vx * Wf[c0 * 3 + 2] + vy * Wf[(c0 + 1) * 3 + 2];
#pragma unroll
    for (int off = 32; off > 0; off >>= 1) {
        p0 += __shfl_xor(p0, off);
        p1 += __shfl_xor(p1, off);
        p2 += __shfl_xor(p2, off);
    }
    if (lane == 0) {
        float l0 = p0 + bf[0], l1 = p1 + bf[1], l2 = p2 + bf[2];
        float mm = fmaxf(l0, fmaxf(l1, l2));
        float lse = mm + logf(expf(l0 - mm) + expf(l1 - mm) + expf(l2 - mm));
        out[(size_t)w * 3 + 0] = l0 - lse;
        out[(size_t)w * 3 + 1] = l1 - lse;
        out[(size_t)w * 3 + 2] = l2 - lse;
    }
}

// ================= launch =================
extern "C" void kernel_launch(void* const* d_in, const int* in_sizes, int n_in,
                              void* d_out, int out_size, void* d_ws, size_t ws_size,
                              hipStream_t stream) {
    const float* x     = (const float*)d_in[0];
    const int*   ei    = (const int*)d_in[1];
    const int*   etype = (const int*)d_in[2];
    const float* Wp    = (const float*)d_in[3];
    const float* bp    = (const float*)d_in[4];
    const float* W1    = (const float*)d_in[5];
    const float* root1 = (const float*)d_in[6];
    const float* b1    = (const float*)d_in[7];
    const float* W2    = (const float*)d_in[8];
    const float* root2 = (const float*)d_in[9];
    const float* b2    = (const float*)d_in[10];
    const float* Wg    = (const float*)d_in[11];
    const float* att   = (const float*)d_in[12];
    const float* bg    = (const float*)d_in[13];
    const float* Wf    = (const float*)d_in[14];
    const float* bf    = (const float*)d_in[15];
    (void)in_sizes; (void)n_in; (void)out_size; (void)ws_size;

    const int* srcv = ei;
    const int* tgtv = ei + EE;

    const int K9 = (RR + 1) * HF;   // 1152

    // ---- workspace layout (bytes), total ~152.2 MB ----
    char* base = (char*)d_ws;
    unsigned short* agg9 = (unsigned short*)(base + 0);           // N*1152*2 = 115,200,000
    unsigned short* xb   = agg9;                                  // alias: consumed before agg9 written
    unsigned short* hb1  = (unsigned short*)(base + 115200000);   // 12,800,000
    unsigned short* hb2  = (unsigned short*)(base + 128000000);   // 12,800,000
    float* a_src         = (float*)(base + 140800000);            // 1,600,000
    float* a_tgt         = (float*)(base + 142400000);            // 1,600,000
    int* csr_src         = (int*)(base + 144000000);              // 3,200,000
    int* csr_rel         = (int*)(base + 147200000);              // 3,200,000
    int* rowptr          = (int*)(base + 150400000);              // 200,016
    int* cursor          = (int*)(base + 150600016);              // 200,000
    unsigned short* Wtp_hi = (unsigned short*)(base + 150800016); // 65,536
    unsigned short* Wtp_lo = (unsigned short*)(base + 150865552); // 65,536
    unsigned short* Wt1_hi = (unsigned short*)(base + 150931088); // 294,912
    unsigned short* Wt1_lo = (unsigned short*)(base + 151226000); // 294,912
    unsigned short* Wt2_hi = (unsigned short*)(base + 151520912); // 294,912
    unsigned short* Wt2_lo = (unsigned short*)(base + 151815824); // 294,912
    unsigned short* Wtg_hi = (unsigned short*)(base + 152110736); // 32,768
    unsigned short* Wtg_lo = (unsigned short*)(base + 152143504); // 32,768

    // ---- converts: x -> bf16; weights -> transposed bf16 hi/lo ----
    cvt_x_kernel<<<cdiv((long long)NN * DIN / 4, 256), 256, 0, stream>>>(x, xb);
    trans_split_kernel<<<cdiv(256 * 128, 256), 256, 0, stream>>>(Wp, Wtp_hi, Wtp_lo, 256, 0, 256);
    trans_split_kernel<<<cdiv(1024 * 128, 256), 256, 0, stream>>>(W1, Wt1_hi, Wt1_lo, 1024, 0, K9);
    trans_split_kernel<<<cdiv(128 * 128, 256), 256, 0, stream>>>(root1, Wt1_hi, Wt1_lo, 128, 1024, K9);
    trans_split_kernel<<<cdiv(1024 * 128, 256), 256, 0, stream>>>(W2, Wt2_hi, Wt2_lo, 1024, 0, K9);
    trans_split_kernel<<<cdiv(128 * 128, 256), 256, 0, stream>>>(root2, Wt2_hi, Wt2_lo, 128, 1024, K9);
    trans_split_kernel<<<cdiv(128 * 128, 256), 256, 0, stream>>>(Wg, Wtg_hi, Wtg_lo, 128, 0, 128);

    // ---- CSR build ----
    hipMemsetAsync(cursor, 0, (size_t)NN * 4, stream);
    count_kernel<<<cdiv(EE, 256), 256, 0, stream>>>(tgtv, cursor);
    scan_kernel<<<1, 1024, 0, stream>>>(cursor, rowptr, cursor);
    fill_kernel<<<cdiv(EE, 256), 256, 0, stream>>>(srcv, tgtv, etype, cursor, csr_src, csr_rel);

    const int ggrid  = cdiv(NN, 128);
    const int nwgrid = cdiv(NN, 4);

    // ---- projection: hb1 = x @ Wp + bp ----
    gemm_mfma<true, false><<<ggrid, 256, 0, stream>>>(xb, DIN, Wtp_hi, Wtp_lo, DIN, hb1, bp, NN, DIN);

    // ---- RGCN layer 1 (fused agg+root GEMM): hb1 -> hb2 ----
    rgcn_agg_all<<<nwgrid, 256, 0, stream>>>(hb1, rowptr, csr_src, csr_rel, agg9);
    gemm_mfma<true, true><<<ggrid, 256, 0, stream>>>(agg9, K9, Wt1_hi, Wt1_lo, K9, hb2, b1, NN, K9);

    // ---- RGCN layer 2: hb2 -> hb1 ----
    rgcn_agg_all<<<nwgrid, 256, 0, stream>>>(hb2, rowptr, csr_src, csr_rel, agg9);
    gemm_mfma<true, true><<<ggrid, 256, 0, stream>>>(agg9, K9, Wt2_hi, Wt2_lo, K9, hb1, b2, NN, K9);

    // ---- GAT: z = hb1 @ Wg -> hb2 ----
    gemm_mfma<false, false><<<ggrid, 256, 0, stream>>>(hb1, HF, Wtg_hi, Wtg_lo, HF, hb2, nullptr, NN, HF);
    att_scores<<<cdiv((long long)NN * NHEADS, 256), 256, 0, stream>>>(hb2, att, a_src, a_tgt);
    gat_kernel<<<nwgrid, 256, 0, stream>>>(rowptr, csr_src, a_src, a_tgt, hb2, bg, Wf, bf, (float*)d_out);
}